// Round 10
// baseline (325.486 us; speedup 1.0000x reference)
//
#include <hip/hip_runtime.h>
#include <hip/hip_bf16.h>
#include <math.h>

// Problem constants (H=W=128 passed as inputs but fixed for this problem)
#define B_ 4
#define HH 128
#define WW 128
#define CC 256
#define LL (HH * WW)          // 16384
#define NROWS (B_ * LL)       // 65536
#define NREL 945              // (2*8-1)*(2*32-1)
#define SCALE 0.17677669529663687f  // 32^-0.5
#define LOG2E 1.4426950408889634f
#define SCALE2 (0.17677669529663687f * 1.4426950408889634f)  // SCALE * log2(e)

typedef __attribute__((ext_vector_type(8))) _Float16 half8;
typedef __attribute__((ext_vector_type(2))) __fp16 fp16x2;
typedef __attribute__((ext_vector_type(4))) float f32x4;
typedef __attribute__((ext_vector_type(8))) unsigned short ushort8v;

// fp16 <-> fp32 (RTNE via v_cvt)
__device__ __forceinline__ unsigned short f2h(float f) {
    union { _Float16 h; unsigned short u; } v;
    v.h = (_Float16)f;
    return v.u;
}
__device__ __forceinline__ float h2f(unsigned short u) {
    union { unsigned short u; _Float16 h; } v;
    v.u = u;
    return (float)v.h;
}
// raw v_exp_f32: computes 2^x. Validated in the R6 attn schedule (5 rounds);
// do NOT move into other schedules without re-validation (R7 lesson).
__device__ __forceinline__ float exp2_raw(float x) {
    float r;
    asm("v_exp_f32 %0, %1" : "=v"(r) : "v"(x));
    return r;
}
// async global->LDS, 16 B per lane (dest = wave-uniform base + lane*16)
__device__ __forceinline__ void gl_lds16(const unsigned short* g, unsigned short* l) {
    __builtin_amdgcn_global_load_lds((const __attribute__((address_space(1))) void*)g,
                                     (__attribute__((address_space(3))) void*)l, 16, 0, 0);
}
// reg-stage 8 fp32 -> 8 fp16 (RTNE, identical to the old convx path) -> LDS 16B
__device__ __forceinline__ void stageA(const float* g, unsigned short* l) {
    float4 a = *(const float4*)g;
    float4 b = *(const float4*)(g + 4);
    ushort8v h;
    h[0] = f2h(a.x); h[1] = f2h(a.y); h[2] = f2h(a.z); h[3] = f2h(a.w);
    h[4] = f2h(b.x); h[5] = f2h(b.y); h[6] = f2h(b.z); h[7] = f2h(b.w);
    *(ushort8v*)l = h;
}

// ---------------------------------------------------------------------------
// DynamicPosBias MLP helpers (same expressions as the validated pos_kernel)
// ---------------------------------------------------------------------------
__device__ inline void ln_relu8(float* v, const float* g, const float* b) {
    float m = 0.f;
#pragma unroll
    for (int j = 0; j < 8; j++) m += v[j];
    m *= 0.125f;
    float var = 0.f;
#pragma unroll
    for (int j = 0; j < 8; j++) { float d = v[j] - m; var += d * d; }
    var *= 0.125f;
    float inv = 1.0f / sqrtf(var + 1e-5f);
#pragma unroll
    for (int j = 0; j < 8; j++) {
        float xn = (v[j] - m) * inv * g[j] + b[j];
        v[j] = xn > 0.f ? xn : 0.f;
    }
}

__device__ inline void mat8x8(const float* in, float* out, const float* w, const float* bias) {
#pragma unroll
    for (int j = 0; j < 8; j++) {
        float s = bias[j];
#pragma unroll
        for (int i = 0; i < 8; i++) s = fmaf(in[i], w[i * 8 + j], s);
        out[j] = s;
    }
}

// ---------------------------------------------------------------------------
// rpb_kernel (FUSED with pos MLP): each thread computes the DynamicPosBias
// MLP for its own (dy,dx) — identical fp expressions to the old pos_kernel,
// so values are bit-identical — and writes the swapped-QK^T C-fragment T2:
// [br][h][qchunk(16)][kc(8)][s(2)][lane(64)][i(4)], value = bias(q,k)*log2e.
// ---------------------------------------------------------------------------
__global__ void rpb_kernel(const float* __restrict__ pp_w, const float* __restrict__ pp_b,
                           const float* __restrict__ ln1_g, const float* __restrict__ ln1_b,
                           const float* __restrict__ l1_w, const float* __restrict__ l1_b,
                           const float* __restrict__ ln2_g, const float* __restrict__ ln2_b,
                           const float* __restrict__ l2_w, const float* __restrict__ l2_b,
                           const float* __restrict__ ln3_g, const float* __restrict__ ln3_b,
                           const float* __restrict__ l3_w, const float* __restrict__ l3_b,
                           float* __restrict__ T2) {
    const int m = threadIdx.x;       // key
    const int n = blockIdx.x;        // query
    const int h = blockIdx.y;
    const int br = blockIdx.z;
    const int logW = br ? 3 : 5;
    const int Wsp = 1 << logW;
    const int i_n = n >> logW, j_n = n & (Wsp - 1);
    const int i_m = m >> logW, j_m = m & (Wsp - 1);

    float dy = (float)(i_n - i_m);
    float dx = (float)(j_n - j_m);
    float p[8], t[8];
#pragma unroll
    for (int j = 0; j < 8; j++)
        p[j] = dy * pp_w[br * 16 + j] + dx * pp_w[br * 16 + 8 + j] + pp_b[br * 8 + j];
    ln_relu8(p, ln1_g + br * 8, ln1_b + br * 8);
    mat8x8(p, t, l1_w + br * 64, l1_b + br * 8);
    ln_relu8(t, ln2_g + br * 8, ln2_b + br * 8);
    mat8x8(t, p, l2_w + br * 64, l2_b + br * 8);
    ln_relu8(p, ln3_g + br * 8, ln3_b + br * 8);
    float s3 = l3_b[br * 4 + h];
#pragma unroll
    for (int i2 = 0; i2 < 8; i2++) s3 = fmaf(p[i2], l3_w[br * 32 + i2 * 4 + h], s3);

    float v = s3 * LOG2E;
    const int qchunk = n >> 4;
    const int l15q = n & 15;
    const int kc = m >> 5;
    const int lk = m & 31;
    const int s = (lk >> 4) & 1;
    const int quad = (lk & 15) >> 2;
    const int i = lk & 3;
    const int lane = quad * 16 + l15q;
    T2[(((size_t)(br * 4 + h) * 16 + qchunk) * 4096) + ((kc * 2 + s) * 256) + lane * 4 + i] = v;
}

// Transpose both weights in one launch: blocks [0,768) -> w_qkv, [768,1024) -> w_proj.
__global__ void convw_all(const float* __restrict__ w_qkv, const float* __restrict__ w_proj,
                          unsigned short* __restrict__ wqh, unsigned short* __restrict__ wph) {
    const int bb = blockIdx.x;
    if (bb < 768) {
        int idx = bb * 256 + threadIdx.x;       // n*K + k, Kd=256, Nd=768
        int n = idx >> 8, k = idx & 255;
        wqh[idx] = f2h(w_qkv[(size_t)k * 768 + n]);
    } else {
        int idx = (bb - 768) * 256 + threadIdx.x;  // Kd=256, Nd=256
        int n = idx >> 8, k = idx & 255;
        wph[idx] = f2h(w_proj[(size_t)k * 256 + n]);
    }
}

// ---------------------------------------------------------------------------
// gemm_f16: C_f16[M][ldc] = X_fp32 @ B_f16^T  (A converted in-kernel, RTNE —
// byte-identical LDS content to the old convx+gl_lds path; convx eliminated).
// BK=64 as two sequential 8 KB sub-tiles; B staged via global_load_lds,
// A reg-staged (load fp32 -> cvt -> ds_write_b128). LDS 32 KB.
// Epilogue: q-columns (col<256) pre-scaled by SCALE2 = scale*log2e.
// ---------------------------------------------------------------------------
__global__ __launch_bounds__(256) void gemm_f16(const float* __restrict__ X,
                                                const unsigned short* __restrict__ B,
                                                unsigned short* __restrict__ C,
                                                int ldc, int nblk) {
    const int K = 256;
    __shared__ unsigned short sA0[4096];  // [128][32] halves, k in [kb, kb+32)
    __shared__ unsigned short sA1[4096];  // k in [kb+32, kb+64)
    __shared__ unsigned short sB0[4096];
    __shared__ unsigned short sB1[4096];

    const int tid = threadIdx.x;
    // XCD-aware bijective swizzle: grid (3072) % 8 == 0
    const int cpx = gridDim.x >> 3;
    const int bid = blockIdx.x;
    const int swz = (bid & 7) * cpx + (bid >> 3);
    const int nb = swz % nblk;                 // N fastest: A-tile L2 reuse
    const int mb = swz / nblk;
    const size_t blockM = (size_t)mb * 128;
    const int blockN = nb * 128;

    const int srow = tid >> 2;                 // staging row 0..63
    const int schunk = (tid & 3) * 8;          // k-chunk
    const float* pX = X + (blockM + srow) * K + schunk;
    const unsigned short* pB = B + (size_t)(blockN + srow) * K + schunk;
    const size_t rstep = (size_t)64 * K;

    const int w = tid >> 6;
    const int lane = tid & 63;
    const int quad = lane >> 4;
    const int l15 = lane & 15;
    const int wm = (w & 1) * 64;
    const int wn = (w >> 1) * 64;

    f32x4 acc[4][4];
#pragma unroll
    for (int i = 0; i < 4; i++)
#pragma unroll
        for (int j = 0; j < 4; j++) acc[i][j] = (f32x4){0.f, 0.f, 0.f, 0.f};

    for (int kb = 0; kb < K; kb += 64) {
        gl_lds16(pB + kb, sB0 + tid * 8);
        gl_lds16(pB + kb + rstep, sB0 + 2048 + tid * 8);
        gl_lds16(pB + kb + 32, sB1 + tid * 8);
        gl_lds16(pB + kb + 32 + rstep, sB1 + 2048 + tid * 8);
        stageA(pX + kb, sA0 + tid * 8);
        stageA(pX + kb + rstep, sA0 + 2048 + tid * 8);
        stageA(pX + kb + 32, sA1 + tid * 8);
        stageA(pX + kb + 32 + rstep, sA1 + 2048 + tid * 8);
        __syncthreads();

        half8 fa[4], fb[4];
#pragma unroll
        for (int i = 0; i < 4; i++) {
            fa[i] = *(const half8*)(sA0 + (wm + i * 16 + l15) * 32 + quad * 8);
            fb[i] = *(const half8*)(sB0 + (wn + i * 16 + l15) * 32 + quad * 8);
        }
#pragma unroll
        for (int i = 0; i < 4; i++)
#pragma unroll
            for (int j = 0; j < 4; j++)
                acc[i][j] = __builtin_amdgcn_mfma_f32_16x16x32_f16(fa[i], fb[j], acc[i][j], 0, 0, 0);
#pragma unroll
        for (int i = 0; i < 4; i++) {
            fa[i] = *(const half8*)(sA1 + (wm + i * 16 + l15) * 32 + quad * 8);
            fb[i] = *(const half8*)(sB1 + (wn + i * 16 + l15) * 32 + quad * 8);
        }
#pragma unroll
        for (int i = 0; i < 4; i++)
#pragma unroll
            for (int j = 0; j < 4; j++)
                acc[i][j] = __builtin_amdgcn_mfma_f32_16x16x32_f16(fa[i], fb[j], acc[i][j], 0, 0, 0);
        __syncthreads();
    }

#pragma unroll
    for (int j = 0; j < 4; j++) {
        int col = blockN + wn + j * 16 + l15;
        // q-columns carry the softmax scale (wave-uniform branch)
        float sc = (ldc == 768 && col < 256) ? SCALE2 : 1.0f;
#pragma unroll
        for (int i = 0; i < 4; i++)
#pragma unroll
            for (int r = 0; r < 4; r++) {
                size_t row = blockM + wm + i * 16 + quad * 4 + r;
                C[row * ldc + col] = f2h(acc[i][j][r] * sc);
            }
    }
}

// ---------------------------------------------------------------------------
// gemm_proj: C_f32[M][256] = A_f16 @ B_f16^T + bias  (single-term, unchanged).
// ---------------------------------------------------------------------------
__global__ __launch_bounds__(256) void gemm_proj(const unsigned short* __restrict__ A,
                                                 const unsigned short* __restrict__ B,
                                                 float* __restrict__ C,
                                                 const float* __restrict__ bias) {
    const int K = 256;
    __shared__ unsigned short sA[4096];
    __shared__ unsigned short sB[4096];

    const int tid = threadIdx.x;
    const int cpx = gridDim.x >> 3;
    const int bid = blockIdx.x;
    const int swz = (bid & 7) * cpx + (bid >> 3);
    const int nb = swz & 1;
    const int mb = swz >> 1;
    const size_t blockM = (size_t)mb * 128;
    const int blockN = nb * 128;

    const int srow = tid >> 2;
    const int schunk = (tid & 3) * 8;
    const unsigned short* pA = A + (blockM + srow) * K + schunk;
    const unsigned short* pB = B + (size_t)(blockN + srow) * K + schunk;
    const size_t rstep = (size_t)64 * K;

    const int w = tid >> 6;
    const int lane = tid & 63;
    const int quad = lane >> 4;
    const int l15 = lane & 15;
    const int wm = (w & 1) * 64;
    const int wn = (w >> 1) * 64;

    f32x4 acc[4][4];
#pragma unroll
    for (int i = 0; i < 4; i++)
#pragma unroll
        for (int j = 0; j < 4; j++) acc[i][j] = (f32x4){0.f, 0.f, 0.f, 0.f};

    for (int kb = 0; kb < K; kb += 32) {
        gl_lds16(pA + kb, sA + tid * 8);
        gl_lds16(pA + kb + rstep, sA + 2048 + tid * 8);
        gl_lds16(pB + kb, sB + tid * 8);
        gl_lds16(pB + kb + rstep, sB + 2048 + tid * 8);
        __syncthreads();

        half8 fa[4], fb[4];
#pragma unroll
        for (int i = 0; i < 4; i++) {
            fa[i] = *(const half8*)(sA + (wm + i * 16 + l15) * 32 + quad * 8);
            fb[i] = *(const half8*)(sB + (wn + i * 16 + l15) * 32 + quad * 8);
        }
#pragma unroll
        for (int i = 0; i < 4; i++)
#pragma unroll
            for (int j = 0; j < 4; j++)
                acc[i][j] = __builtin_amdgcn_mfma_f32_16x16x32_f16(fa[i], fb[j], acc[i][j], 0, 0, 0);
        __syncthreads();
    }

#pragma unroll
    for (int j = 0; j < 4; j++) {
        int col = blockN + wn + j * 16 + l15;
        float bv = bias[col];
#pragma unroll
        for (int i = 0; i < 4; i++)
#pragma unroll
            for (int r = 0; r < 4; r++) {
                size_t row = blockM + wm + i * 16 + quad * 4 + r;
                C[row * 256 + col] = acc[i][j][r] + bv;
            }
    }
}

// ---------------------------------------------------------------------------
// MFMA window attention — EXACT R6/R9-validated kernel (52.5 µs). Swapped-
// operand zero-shuffle softmax; qt-outer / kc-inner schedule.
// LDS: Ks 16384 + Vt 16896 = 33280 B -> 4 blocks/CU.
// ---------------------------------------------------------------------------
__global__ __launch_bounds__(256) void attn_mfma(const unsigned short* __restrict__ qkvb,
                                                 const float* __restrict__ T2,
                                                 unsigned short* __restrict__ attb) {
    __shared__ unsigned short Ks[256][32];    // [key][d], natural key order
    __shared__ unsigned short Vt[32][264];    // [d][key-slot(permuted)]

    const int tid = threadIdx.x;
    const int wi = blockIdx.x;   // b*64 + window
    const int h = blockIdx.y;    // 0..3
    const int br = blockIdx.z;   // 0..1
    const int logW = br ? 3 : 5;
    const int Wsp = 1 << logW;
    const int Hsp = 256 >> logW;
    const int logNWx = br ? 4 : 2;
    const int b = wi >> 6;
    const int win = wi & 63;
    const int wy = win >> logNWx;
    const int wx = win & ((1 << logNWx) - 1);
    const int ccol = br * 128 + h * 32;

#pragma unroll
    for (int it = 0; it < 8; ++it) {
        int n = it * 32 + (tid >> 3);
        int d4 = (tid & 7) * 4;
        int iy = n >> logW, ix = n & (Wsp - 1);
        size_t row = ((size_t)b * LL + (wy * Hsp + iy) * WW + wx * Wsp + ix) * 768;
        ushort4 kv = *(const ushort4*)(qkvb + row + 256 + ccol + d4);
        ushort4 vv = *(const ushort4*)(qkvb + row + 512 + ccol + d4);
        *(ushort4*)&Ks[n][d4] = kv;
        // slot-permuted key position within each 32-key chunk
        int pos = (n & ~31) + (((n & 12) << 1) | ((n & 16) >> 2) | (n & 3));
        Vt[d4 + 0][pos] = vv.x;
        Vt[d4 + 1][pos] = vv.y;
        Vt[d4 + 2][pos] = vv.z;
        Vt[d4 + 3][pos] = vv.w;
    }
    __syncthreads();

    const int w = tid >> 6;
    const int lane = tid & 63;
    const int quad = lane >> 4;
    const int l15 = lane & 15;
    const f32x4 zero = {0.f, 0.f, 0.f, 0.f};

#pragma unroll 1
    for (int qt = 0; qt < 4; ++qt) {
        const int qbase = qt * 64 + w * 16;
        const int qrow = qbase + l15;
        const int iyq = qrow >> logW, ixq = qrow & (Wsp - 1);
        const size_t qpix = (size_t)b * LL + (wy * Hsp + iyq) * WW + wx * Wsp + ixq;
        half8 qfrag = *(const half8*)(qkvb + qpix * 768 + ccol + quad * 8);

        // swapped-layout bias base for this wave's 16-query chunk
        const float* Tf = T2 + ((size_t)(br * 4 + h) * 16 + (qt * 4 + w)) * 4096 + lane * 4;

        f32x4 o0 = zero, o1 = zero;
        float rsum = 0.f;

#pragma unroll 2
        for (int kc = 0; kc < 8; ++kc) {
            const int kb0 = kc * 32;
            f32x4 b0 = *(const f32x4*)(Tf + kc * 512);
            f32x4 b1 = *(const f32x4*)(Tf + kc * 512 + 256);
            half8 kf0 = *(const half8*)&Ks[kb0 + l15][quad * 8];
            half8 kf1 = *(const half8*)&Ks[kb0 + 16 + l15][quad * 8];
            // S^T = K · Q^T + bias  (rows = keys, cols = queries)
            f32x4 s0 = __builtin_amdgcn_mfma_f32_16x16x32_f16(kf0, qfrag, b0, 0, 0, 0);
            f32x4 s1 = __builtin_amdgcn_mfma_f32_16x16x32_f16(kf1, qfrag, b1, 0, 0, 0);
            float e00 = exp2_raw(s0[0]), e01 = exp2_raw(s0[1]);
            float e02 = exp2_raw(s0[2]), e03 = exp2_raw(s0[3]);
            float e10 = exp2_raw(s1[0]), e11 = exp2_raw(s1[1]);
            float e12 = exp2_raw(s1[2]), e13 = exp2_raw(s1[3]);
            rsum += ((e00 + e01) + (e02 + e03)) + ((e10 + e11) + (e12 + e13));
            union { half8 h; unsigned u[4]; } pt;
            union { fp16x2 h; unsigned u; } cv;
            cv.h = __builtin_amdgcn_cvt_pkrtz(e00, e01); pt.u[0] = cv.u;
            cv.h = __builtin_amdgcn_cvt_pkrtz(e02, e03); pt.u[1] = cv.u;
            cv.h = __builtin_amdgcn_cvt_pkrtz(e10, e11); pt.u[2] = cv.u;
            cv.h = __builtin_amdgcn_cvt_pkrtz(e12, e13); pt.u[3] = cv.u;
            half8 vf0 = *(const half8*)&Vt[l15][kb0 + quad * 8];
            half8 vf1 = *(const half8*)&Vt[16 + l15][kb0 + quad * 8];
            // o^T = V^T · P^T  (rows = d, cols = queries)
            o0 = __builtin_amdgcn_mfma_f32_16x16x32_f16(vf0, pt.h, o0, 0, 0, 0);
            o1 = __builtin_amdgcn_mfma_f32_16x16x32_f16(vf1, pt.h, o1, 0, 0, 0);
        }

        // full row-sum for query l15: reduce across the 4 quads
        rsum += __shfl_xor(rsum, 16, 64);
        rsum += __shfl_xor(rsum, 32, 64);
        const float rinv = 1.0f / rsum;

        unsigned short* op = attb + qpix * 256 + ccol;
        ushort4 w0, w1;
        w0.x = f2h(o0[0] * rinv); w0.y = f2h(o0[1] * rinv);
        w0.z = f2h(o0[2] * rinv); w0.w = f2h(o0[3] * rinv);
        w1.x = f2h(o1[0] * rinv); w1.y = f2h(o1[1] * rinv);
        w1.z = f2h(o1[2] * rinv); w1.w = f2h(o1[3] * rinv);
        *(ushort4*)(op + quad * 4) = w0;
        *(ushort4*)(op + 16 + quad * 4) = w1;
    }
}

// ---------------------------------------------------------------------------
// LePE: depthwise 3x3 on fp16 V, += (with bias) into fp16 attb (RMW).
// Column-sliding-window (validated R5): 3 V loads + 1 RMW per pixel.
// ---------------------------------------------------------------------------
__global__ __launch_bounds__(256) void lepe_kernel(const unsigned short* __restrict__ qkvb,
                                                   const float* __restrict__ w_dw,
                                                   const float* __restrict__ b_dw,
                                                   unsigned short* __restrict__ attb) {
    const int lane = threadIdx.x & 63;
    const int wv = threadIdx.x >> 6;
    const int c4 = lane * 4;
    const int gid = blockIdx.x * 4 + wv;     // 4096 waves total
    const int ys = gid & 7;                  // y-strip of 16 rows
    const int x  = (gid >> 3) & 127;
    const int b  = gid >> 10;
    const int y0 = ys * 16;

    float wreg[36];
    const float* wp = w_dw + c4 * 9;
#pragma unroll
    for (int q = 0; q < 9; q++) {
        float4 t = *(const float4*)(wp + q * 4);
        wreg[q * 4 + 0] = t.x; wreg[q * 4 + 1] = t.y;
        wreg[q * 4 + 2] = t.z; wreg[q * 4 + 3] = t.w;
    }
    const float4 bv = *(const float4*)(b_dw + c4);
    const float4 z4 = {0.f, 0.f, 0.f, 0.f};
    const bool xm_ok = (x > 0), xp_ok = (x < 127);

    // V address of (b, yy, x+dx): vp + yy*98304 + dx*768
    const unsigned short* vp = qkvb + (((size_t)b << 14) + x) * 768 + 512 + c4;

    float4 r0[3], r1[3], r2[3];

#define LDV(yy, dx, dst) { \
        ushort4 u = *(const ushort4*)(vp + (ptrdiff_t)(yy) * 98304 + (dx) * 768); \
        dst.x = h2f(u.x); dst.y = h2f(u.y); dst.z = h2f(u.z); dst.w = h2f(u.w); }
#define LDROW(yy, d) { \
        if ((yy) < 0 || (yy) > 127) { d[0] = z4; d[1] = z4; d[2] = z4; } \
        else { \
            if (xm_ok) LDV(yy, -1, d[0]) else d[0] = z4; \
            LDV(yy, 0, d[1]); \
            if (xp_ok) LDV(yy, 1, d[2]) else d[2] = z4; } }
#define TAP(rv, j) \
        acc.x = fmaf(rv.x, wreg[0 * 9 + (j)], acc.x); \
        acc.y = fmaf(rv.y, wreg[1 * 9 + (j)], acc.y); \
        acc.z = fmaf(rv.z, wreg[2 * 9 + (j)], acc.z); \
        acc.w = fmaf(rv.w, wreg[3 * 9 + (j)], acc.w);

    LDROW(y0 - 1, r0)
    LDROW(y0, r1)

#pragma unroll
    for (int t = 0; t < 16; ++t) {
        const int y = y0 + t;
        LDROW(y + 1, r2)

        const size_t opx = ((((size_t)b << 14) + y * 128 + x) << 8) + c4;
        ushort4 av = *(const ushort4*)(attb + opx);
        float4 acc;
        acc.x = h2f(av.x) + bv.x; acc.y = h2f(av.y) + bv.y;
        acc.z = h2f(av.z) + bv.z; acc.w = h2f(av.w) + bv.w;

        TAP(r0[0], 0) TAP(r0[1], 1) TAP(r0[2], 2)
        TAP(r1[0], 3) TAP(r1[1], 4) TAP(r1[2], 5)
        TAP(r2[0], 6) TAP(r2[1], 7) TAP(r2[2], 8)

        ushort4 o;
        o.x = f2h(acc.x); o.y = f2h(acc.y); o.z = f2h(acc.z); o.w = f2h(acc.w);
        *(ushort4*)(attb + opx) = o;

        r0[0] = r1[0]; r0[1] = r1[1]; r0[2] = r1[2];
        r1[0] = r2[0]; r1[1] = r2[1]; r1[2] = r2[2];
    }
#undef LDV
#undef LDROW
#undef TAP
}

// ---------------------------------------------------------------------------
extern "C" void kernel_launch(void* const* d_in, const int* in_sizes, int n_in,
                              void* d_out, int out_size, void* d_ws, size_t ws_size,
                              hipStream_t stream) {
    const float* x     = (const float*)d_in[0];
    const float* w_qkv = (const float*)d_in[1];
    const float* w_proj= (const float*)d_in[2];
    const float* b_proj= (const float*)d_in[3];
    const float* w_dw  = (const float*)d_in[4];
    const float* b_dw  = (const float*)d_in[5];
    const float* pp_w  = (const float*)d_in[6];
    const float* pp_b  = (const float*)d_in[7];
    const float* ln1_g = (const float*)d_in[8];
    const float* ln1_b = (const float*)d_in[9];
    const float* l1_w  = (const float*)d_in[10];
    const float* l1_b  = (const float*)d_in[11];
    const float* ln2_g = (const float*)d_in[12];
    const float* ln2_b = (const float*)d_in[13];
    const float* l2_w  = (const float*)d_in[14];
    const float* l2_b  = (const float*)d_in[15];
    const float* ln3_g = (const float*)d_in[16];
    const float* ln3_b = (const float*)d_in[17];
    const float* l3_w  = (const float*)d_in[18];
    const float* l3_b  = (const float*)d_in[19];

    // Workspace layout (~130.5 MiB):
    float* T2  = (float*)d_ws;                               // 524,288 f (swapped frag layout)
    unsigned short* qkvb = (unsigned short*)(T2 + 524288);   // 65536*768 sh (96 MiB, fp16)
    unsigned short* attb = qkvb + (size_t)NROWS * 768;       // 65536*256 sh (32 MiB, fp16)
    unsigned short* wqh  = attb + (size_t)NROWS * 256;       // 196,608 sh
    unsigned short* wph  = wqh + 768 * 256;                  // 65,536 sh

    // T2 bias table (pos MLP fused per-thread)
    rpb_kernel<<<dim3(256, 4, 2), 256, 0, stream>>>(pp_w, pp_b, ln1_g, ln1_b, l1_w, l1_b,
                                                    ln2_g, ln2_b, l2_w, l2_b, ln3_g, ln3_b,
                                                    l3_w, l3_b, T2);
    // both weight transposes in one launch
    convw_all<<<1024, 256, 0, stream>>>(w_qkv, w_proj, wqh, wph);
    // qkv_f16 = x(fp32) @ w_qkv   (A converted in-kernel; q-cols pre-scaled by SCALE2)
    gemm_f16<<<(NROWS / 128) * 6, 256, 0, stream>>>(x, wqh, qkvb, 768, 6);
    // window attention -> attb (fp16, R6-validated qt-outer schedule)
    attn_mfma<<<dim3(256, 4, 2), 256, 0, stream>>>(qkvb, T2, attb);
    // LePE += depthwise conv on V (fp16 RMW, column-sliding-window)
    lepe_kernel<<<1024, 256, 0, stream>>>(qkvb, w_dw, b_dw, attb);
    // d_out = attb @ w_proj + b_proj  (single-term fp16, fp32 out, direct to d_out)
    gemm_proj<<<(NROWS / 128) * 2, 256, 0, stream>>>(attb, wph, (float*)d_out, b_proj);
}

// Round 11
// 310.487 us; speedup vs baseline: 1.0483x; 1.0483x over previous
//
#include <hip/hip_runtime.h>
#include <hip/hip_bf16.h>
#include <math.h>

// Problem constants (H=W=128 passed as inputs but fixed for this problem)
#define B_ 4
#define HH 128
#define WW 128
#define CC 256
#define LL (HH * WW)          // 16384
#define NROWS (B_ * LL)       // 65536
#define NREL 945              // (2*8-1)*(2*32-1)
#define SCALE 0.17677669529663687f  // 32^-0.5
#define LOG2E 1.4426950408889634f
#define SCALE2 (0.17677669529663687f * 1.4426950408889634f)  // SCALE * log2(e)

typedef __attribute__((ext_vector_type(8))) _Float16 half8;
typedef __attribute__((ext_vector_type(2))) __fp16 fp16x2;
typedef __attribute__((ext_vector_type(4))) float f32x4;

// fp16 <-> fp32 (RTNE via v_cvt)
__device__ __forceinline__ unsigned short f2h(float f) {
    union { _Float16 h; unsigned short u; } v;
    v.h = (_Float16)f;
    return v.u;
}
__device__ __forceinline__ float h2f(unsigned short u) {
    union { unsigned short u; _Float16 h; } v;
    v.u = u;
    return (float)v.h;
}
// raw v_exp_f32: computes 2^x. Validated in the R6 attn schedule (6 rounds);
// do NOT move into other schedules without re-validation (R7 lesson).
__device__ __forceinline__ float exp2_raw(float x) {
    float r;
    asm("v_exp_f32 %0, %1" : "=v"(r) : "v"(x));
    return r;
}
// async global->LDS, 16 B per lane (dest = wave-uniform base + lane*16)
__device__ __forceinline__ void gl_lds16(const unsigned short* g, unsigned short* l) {
    __builtin_amdgcn_global_load_lds((const __attribute__((address_space(1))) void*)g,
                                     (__attribute__((address_space(3))) void*)l, 16, 0, 0);
}

// ---------------------------------------------------------------------------
// DynamicPosBias MLP helpers (same expressions as the validated pos_kernel)
// ---------------------------------------------------------------------------
__device__ inline void ln_relu8(float* v, const float* g, const float* b) {
    float m = 0.f;
#pragma unroll
    for (int j = 0; j < 8; j++) m += v[j];
    m *= 0.125f;
    float var = 0.f;
#pragma unroll
    for (int j = 0; j < 8; j++) { float d = v[j] - m; var += d * d; }
    var *= 0.125f;
    float inv = 1.0f / sqrtf(var + 1e-5f);
#pragma unroll
    for (int j = 0; j < 8; j++) {
        float xn = (v[j] - m) * inv * g[j] + b[j];
        v[j] = xn > 0.f ? xn : 0.f;
    }
}

__device__ inline void mat8x8(const float* in, float* out, const float* w, const float* bias) {
#pragma unroll
    for (int j = 0; j < 8; j++) {
        float s = bias[j];
#pragma unroll
        for (int i = 0; i < 8; i++) s = fmaf(in[i], w[i * 8 + j], s);
        out[j] = s;
    }
}

// ---------------------------------------------------------------------------
// rpb_kernel (pos MLP fused per-thread, validated R10): computes the
// DynamicPosBias MLP for its own (dy,dx) and writes the swapped-QK^T
// C-fragment T2: [br][h][qchunk(16)][kc(8)][s(2)][lane(64)][i(4)],
// value = bias(q,k)*log2e.
// ---------------------------------------------------------------------------
__global__ void rpb_kernel(const float* __restrict__ pp_w, const float* __restrict__ pp_b,
                           const float* __restrict__ ln1_g, const float* __restrict__ ln1_b,
                           const float* __restrict__ l1_w, const float* __restrict__ l1_b,
                           const float* __restrict__ ln2_g, const float* __restrict__ ln2_b,
                           const float* __restrict__ l2_w, const float* __restrict__ l2_b,
                           const float* __restrict__ ln3_g, const float* __restrict__ ln3_b,
                           const float* __restrict__ l3_w, const float* __restrict__ l3_b,
                           float* __restrict__ T2) {
    const int m = threadIdx.x;       // key
    const int n = blockIdx.x;        // query
    const int h = blockIdx.y;
    const int br = blockIdx.z;
    const int logW = br ? 3 : 5;
    const int Wsp = 1 << logW;
    const int i_n = n >> logW, j_n = n & (Wsp - 1);
    const int i_m = m >> logW, j_m = m & (Wsp - 1);

    float dy = (float)(i_n - i_m);
    float dx = (float)(j_n - j_m);
    float p[8], t[8];
#pragma unroll
    for (int j = 0; j < 8; j++)
        p[j] = dy * pp_w[br * 16 + j] + dx * pp_w[br * 16 + 8 + j] + pp_b[br * 8 + j];
    ln_relu8(p, ln1_g + br * 8, ln1_b + br * 8);
    mat8x8(p, t, l1_w + br * 64, l1_b + br * 8);
    ln_relu8(t, ln2_g + br * 8, ln2_b + br * 8);
    mat8x8(t, p, l2_w + br * 64, l2_b + br * 8);
    ln_relu8(p, ln3_g + br * 8, ln3_b + br * 8);
    float s3 = l3_b[br * 4 + h];
#pragma unroll
    for (int i2 = 0; i2 < 8; i2++) s3 = fmaf(p[i2], l3_w[br * 32 + i2 * 4 + h], s3);

    float v = s3 * LOG2E;
    const int qchunk = n >> 4;
    const int l15q = n & 15;
    const int kc = m >> 5;
    const int lk = m & 31;
    const int s = (lk >> 4) & 1;
    const int quad = (lk & 15) >> 2;
    const int i = lk & 3;
    const int lane = quad * 16 + l15q;
    T2[(((size_t)(br * 4 + h) * 16 + qchunk) * 4096) + ((kc * 2 + s) * 256) + lane * 4 + i] = v;
}

// Transpose both weights in one launch: blocks [0,768) -> w_qkv, [768,1024) -> w_proj.
__global__ void convw_all(const float* __restrict__ w_qkv, const float* __restrict__ w_proj,
                          unsigned short* __restrict__ wqh, unsigned short* __restrict__ wph) {
    const int bb = blockIdx.x;
    if (bb < 768) {
        int idx = bb * 256 + threadIdx.x;       // n*K + k, Kd=256, Nd=768
        int n = idx >> 8, k = idx & 255;
        wqh[idx] = f2h(w_qkv[(size_t)k * 768 + n]);
    } else {
        int idx = (bb - 768) * 256 + threadIdx.x;  // Kd=256, Nd=256
        int n = idx >> 8, k = idx & 255;
        wph[idx] = f2h(w_proj[(size_t)k * 256 + n]);
    }
}

// x fp32 [M][256] -> xh fp16 (row-major) — restored (R10 lesson: in-GEMM
// conversion forces reg-staging, losing the async global_load_lds path).
__global__ __launch_bounds__(256) void convx_kernel(const float* __restrict__ x,
                                                    unsigned short* __restrict__ xh) {
    size_t i = ((size_t)blockIdx.x * 256 + threadIdx.x) * 4;
    float4 v = *(const float4*)(x + i);
    ushort4 h;
    h.x = f2h(v.x); h.y = f2h(v.y); h.z = f2h(v.z); h.w = f2h(v.w);
    *(ushort4*)(xh + i) = h;
}

// ---------------------------------------------------------------------------
// gemm_f16: C_f16[M][ldc] = A_f16 @ B_f16^T  (single-term, m97 structure,
// EXACT R6-validated kernel). BK=32, global_load_lds staging both operands.
// Epilogue: q-columns (col<256) pre-scaled by SCALE2 = scale*log2e.
// ---------------------------------------------------------------------------
__global__ __launch_bounds__(256) void gemm_f16(const unsigned short* __restrict__ A,
                                                const unsigned short* __restrict__ B,
                                                unsigned short* __restrict__ C,
                                                int ldc, int nblk) {
    const int K = 256;
    __shared__ unsigned short sA[4096];  // [128][32]
    __shared__ unsigned short sB[4096];

    const int tid = threadIdx.x;
    // XCD-aware bijective swizzle: grid (3072) % 8 == 0
    const int cpx = gridDim.x >> 3;
    const int bid = blockIdx.x;
    const int swz = (bid & 7) * cpx + (bid >> 3);
    const int nb = swz % nblk;                 // N fastest: A-tile L2 reuse
    const int mb = swz / nblk;
    const size_t blockM = (size_t)mb * 128;
    const int blockN = nb * 128;

    const int srow = tid >> 2;                 // staging row 0..63
    const int schunk = (tid & 3) * 8;          // k-chunk
    const unsigned short* pA = A + (blockM + srow) * K + schunk;
    const unsigned short* pB = B + (size_t)(blockN + srow) * K + schunk;
    const size_t rstep = (size_t)64 * K;

    const int w = tid >> 6;
    const int lane = tid & 63;
    const int quad = lane >> 4;
    const int l15 = lane & 15;
    const int wm = (w & 1) * 64;
    const int wn = (w >> 1) * 64;

    f32x4 acc[4][4];
#pragma unroll
    for (int i = 0; i < 4; i++)
#pragma unroll
        for (int j = 0; j < 4; j++) acc[i][j] = (f32x4){0.f, 0.f, 0.f, 0.f};

    for (int kb = 0; kb < K; kb += 32) {
        gl_lds16(pA + kb, sA + tid * 8);
        gl_lds16(pA + kb + rstep, sA + 2048 + tid * 8);
        gl_lds16(pB + kb, sB + tid * 8);
        gl_lds16(pB + kb + rstep, sB + 2048 + tid * 8);
        __syncthreads();

        half8 fa[4], fb[4];
#pragma unroll
        for (int i = 0; i < 4; i++) {
            fa[i] = *(const half8*)(sA + (wm + i * 16 + l15) * 32 + quad * 8);
            fb[i] = *(const half8*)(sB + (wn + i * 16 + l15) * 32 + quad * 8);
        }
#pragma unroll
        for (int i = 0; i < 4; i++)
#pragma unroll
            for (int j = 0; j < 4; j++)
                acc[i][j] = __builtin_amdgcn_mfma_f32_16x16x32_f16(fa[i], fb[j], acc[i][j], 0, 0, 0);
        __syncthreads();
    }

#pragma unroll
    for (int j = 0; j < 4; j++) {
        int col = blockN + wn + j * 16 + l15;
        // q-columns carry the softmax scale (wave-uniform branch)
        float sc = (ldc == 768 && col < 256) ? SCALE2 : 1.0f;
#pragma unroll
        for (int i = 0; i < 4; i++)
#pragma unroll
            for (int r = 0; r < 4; r++) {
                size_t row = blockM + wm + i * 16 + quad * 4 + r;
                C[row * ldc + col] = f2h(acc[i][j][r] * sc);
            }
    }
}

// ---------------------------------------------------------------------------
// gemm_proj: C_f32[M][256] = A_f16 @ B_f16^T + bias  (single-term, unchanged).
// ---------------------------------------------------------------------------
__global__ __launch_bounds__(256) void gemm_proj(const unsigned short* __restrict__ A,
                                                 const unsigned short* __restrict__ B,
                                                 float* __restrict__ C,
                                                 const float* __restrict__ bias) {
    const int K = 256;
    __shared__ unsigned short sA[4096];
    __shared__ unsigned short sB[4096];

    const int tid = threadIdx.x;
    const int cpx = gridDim.x >> 3;
    const int bid = blockIdx.x;
    const int swz = (bid & 7) * cpx + (bid >> 3);
    const int nb = swz & 1;
    const int mb = swz >> 1;
    const size_t blockM = (size_t)mb * 128;
    const int blockN = nb * 128;

    const int srow = tid >> 2;
    const int schunk = (tid & 3) * 8;
    const unsigned short* pA = A + (blockM + srow) * K + schunk;
    const unsigned short* pB = B + (size_t)(blockN + srow) * K + schunk;
    const size_t rstep = (size_t)64 * K;

    const int w = tid >> 6;
    const int lane = tid & 63;
    const int quad = lane >> 4;
    const int l15 = lane & 15;
    const int wm = (w & 1) * 64;
    const int wn = (w >> 1) * 64;

    f32x4 acc[4][4];
#pragma unroll
    for (int i = 0; i < 4; i++)
#pragma unroll
        for (int j = 0; j < 4; j++) acc[i][j] = (f32x4){0.f, 0.f, 0.f, 0.f};

    for (int kb = 0; kb < K; kb += 32) {
        gl_lds16(pA + kb, sA + tid * 8);
        gl_lds16(pA + kb + rstep, sA + 2048 + tid * 8);
        gl_lds16(pB + kb, sB + tid * 8);
        gl_lds16(pB + kb + rstep, sB + 2048 + tid * 8);
        __syncthreads();

        half8 fa[4], fb[4];
#pragma unroll
        for (int i = 0; i < 4; i++) {
            fa[i] = *(const half8*)(sA + (wm + i * 16 + l15) * 32 + quad * 8);
            fb[i] = *(const half8*)(sB + (wn + i * 16 + l15) * 32 + quad * 8);
        }
#pragma unroll
        for (int i = 0; i < 4; i++)
#pragma unroll
            for (int j = 0; j < 4; j++)
                acc[i][j] = __builtin_amdgcn_mfma_f32_16x16x32_f16(fa[i], fb[j], acc[i][j], 0, 0, 0);
        __syncthreads();
    }

#pragma unroll
    for (int j = 0; j < 4; j++) {
        int col = blockN + wn + j * 16 + l15;
        float bv = bias[col];
#pragma unroll
        for (int i = 0; i < 4; i++)
#pragma unroll
            for (int r = 0; r < 4; r++) {
                size_t row = blockM + wm + i * 16 + quad * 4 + r;
                C[row * 256 + col] = acc[i][j][r] + bv;
            }
    }
}

// ---------------------------------------------------------------------------
// MFMA window attention — EXACT R6/R9-validated kernel (52.5 µs). Swapped-
// operand zero-shuffle softmax; qt-outer / kc-inner schedule.
// LDS: Ks 16384 + Vt 16896 = 33280 B -> 4 blocks/CU.
// ---------------------------------------------------------------------------
__global__ __launch_bounds__(256) void attn_mfma(const unsigned short* __restrict__ qkvb,
                                                 const float* __restrict__ T2,
                                                 unsigned short* __restrict__ attb) {
    __shared__ unsigned short Ks[256][32];    // [key][d], natural key order
    __shared__ unsigned short Vt[32][264];    // [d][key-slot(permuted)]

    const int tid = threadIdx.x;
    const int wi = blockIdx.x;   // b*64 + window
    const int h = blockIdx.y;    // 0..3
    const int br = blockIdx.z;   // 0..1
    const int logW = br ? 3 : 5;
    const int Wsp = 1 << logW;
    const int Hsp = 256 >> logW;
    const int logNWx = br ? 4 : 2;
    const int b = wi >> 6;
    const int win = wi & 63;
    const int wy = win >> logNWx;
    const int wx = win & ((1 << logNWx) - 1);
    const int ccol = br * 128 + h * 32;

#pragma unroll
    for (int it = 0; it < 8; ++it) {
        int n = it * 32 + (tid >> 3);
        int d4 = (tid & 7) * 4;
        int iy = n >> logW, ix = n & (Wsp - 1);
        size_t row = ((size_t)b * LL + (wy * Hsp + iy) * WW + wx * Wsp + ix) * 768;
        ushort4 kv = *(const ushort4*)(qkvb + row + 256 + ccol + d4);
        ushort4 vv = *(const ushort4*)(qkvb + row + 512 + ccol + d4);
        *(ushort4*)&Ks[n][d4] = kv;
        // slot-permuted key position within each 32-key chunk
        int pos = (n & ~31) + (((n & 12) << 1) | ((n & 16) >> 2) | (n & 3));
        Vt[d4 + 0][pos] = vv.x;
        Vt[d4 + 1][pos] = vv.y;
        Vt[d4 + 2][pos] = vv.z;
        Vt[d4 + 3][pos] = vv.w;
    }
    __syncthreads();

    const int w = tid >> 6;
    const int lane = tid & 63;
    const int quad = lane >> 4;
    const int l15 = lane & 15;
    const f32x4 zero = {0.f, 0.f, 0.f, 0.f};

#pragma unroll 1
    for (int qt = 0; qt < 4; ++qt) {
        const int qbase = qt * 64 + w * 16;
        const int qrow = qbase + l15;
        const int iyq = qrow >> logW, ixq = qrow & (Wsp - 1);
        const size_t qpix = (size_t)b * LL + (wy * Hsp + iyq) * WW + wx * Wsp + ixq;
        half8 qfrag = *(const half8*)(qkvb + qpix * 768 + ccol + quad * 8);

        // swapped-layout bias base for this wave's 16-query chunk
        const float* Tf = T2 + ((size_t)(br * 4 + h) * 16 + (qt * 4 + w)) * 4096 + lane * 4;

        f32x4 o0 = zero, o1 = zero;
        float rsum = 0.f;

#pragma unroll 2
        for (int kc = 0; kc < 8; ++kc) {
            const int kb0 = kc * 32;
            f32x4 b0 = *(const f32x4*)(Tf + kc * 512);
            f32x4 b1 = *(const f32x4*)(Tf + kc * 512 + 256);
            half8 kf0 = *(const half8*)&Ks[kb0 + l15][quad * 8];
            half8 kf1 = *(const half8*)&Ks[kb0 + 16 + l15][quad * 8];
            // S^T = K · Q^T + bias  (rows = keys, cols = queries)
            f32x4 s0 = __builtin_amdgcn_mfma_f32_16x16x32_f16(kf0, qfrag, b0, 0, 0, 0);
            f32x4 s1 = __builtin_amdgcn_mfma_f32_16x16x32_f16(kf1, qfrag, b1, 0, 0, 0);
            float e00 = exp2_raw(s0[0]), e01 = exp2_raw(s0[1]);
            float e02 = exp2_raw(s0[2]), e03 = exp2_raw(s0[3]);
            float e10 = exp2_raw(s1[0]), e11 = exp2_raw(s1[1]);
            float e12 = exp2_raw(s1[2]), e13 = exp2_raw(s1[3]);
            rsum += ((e00 + e01) + (e02 + e03)) + ((e10 + e11) + (e12 + e13));
            union { half8 h; unsigned u[4]; } pt;
            union { fp16x2 h; unsigned u; } cv;
            cv.h = __builtin_amdgcn_cvt_pkrtz(e00, e01); pt.u[0] = cv.u;
            cv.h = __builtin_amdgcn_cvt_pkrtz(e02, e03); pt.u[1] = cv.u;
            cv.h = __builtin_amdgcn_cvt_pkrtz(e10, e11); pt.u[2] = cv.u;
            cv.h = __builtin_amdgcn_cvt_pkrtz(e12, e13); pt.u[3] = cv.u;
            half8 vf0 = *(const half8*)&Vt[l15][kb0 + quad * 8];
            half8 vf1 = *(const half8*)&Vt[16 + l15][kb0 + quad * 8];
            // o^T = V^T · P^T  (rows = d, cols = queries)
            o0 = __builtin_amdgcn_mfma_f32_16x16x32_f16(vf0, pt.h, o0, 0, 0, 0);
            o1 = __builtin_amdgcn_mfma_f32_16x16x32_f16(vf1, pt.h, o1, 0, 0, 0);
        }

        // full row-sum for query l15: reduce across the 4 quads
        rsum += __shfl_xor(rsum, 16, 64);
        rsum += __shfl_xor(rsum, 32, 64);
        const float rinv = 1.0f / rsum;

        unsigned short* op = attb + qpix * 256 + ccol;
        ushort4 w0, w1;
        w0.x = f2h(o0[0] * rinv); w0.y = f2h(o0[1] * rinv);
        w0.z = f2h(o0[2] * rinv); w0.w = f2h(o0[3] * rinv);
        w1.x = f2h(o1[0] * rinv); w1.y = f2h(o1[1] * rinv);
        w1.z = f2h(o1[2] * rinv); w1.w = f2h(o1[3] * rinv);
        *(ushort4*)(op + quad * 4) = w0;
        *(ushort4*)(op + 16 + quad * 4) = w1;
    }
}

// ---------------------------------------------------------------------------
// LePE: depthwise 3x3 on fp16 V, += (with bias) into fp16 attb (RMW).
// Column-sliding-window (validated R5): 3 V loads + 1 RMW per pixel.
// ---------------------------------------------------------------------------
__global__ __launch_bounds__(256) void lepe_kernel(const unsigned short* __restrict__ qkvb,
                                                   const float* __restrict__ w_dw,
                                                   const float* __restrict__ b_dw,
                                                   unsigned short* __restrict__ attb) {
    const int lane = threadIdx.x & 63;
    const int wv = threadIdx.x >> 6;
    const int c4 = lane * 4;
    const int gid = blockIdx.x * 4 + wv;     // 4096 waves total
    const int ys = gid & 7;                  // y-strip of 16 rows
    const int x  = (gid >> 3) & 127;
    const int b  = gid >> 10;
    const int y0 = ys * 16;

    float wreg[36];
    const float* wp = w_dw + c4 * 9;
#pragma unroll
    for (int q = 0; q < 9; q++) {
        float4 t = *(const float4*)(wp + q * 4);
        wreg[q * 4 + 0] = t.x; wreg[q * 4 + 1] = t.y;
        wreg[q * 4 + 2] = t.z; wreg[q * 4 + 3] = t.w;
    }
    const float4 bv = *(const float4*)(b_dw + c4);
    const float4 z4 = {0.f, 0.f, 0.f, 0.f};
    const bool xm_ok = (x > 0), xp_ok = (x < 127);

    // V address of (b, yy, x+dx): vp + yy*98304 + dx*768
    const unsigned short* vp = qkvb + (((size_t)b << 14) + x) * 768 + 512 + c4;

    float4 r0[3], r1[3], r2[3];

#define LDV(yy, dx, dst) { \
        ushort4 u = *(const ushort4*)(vp + (ptrdiff_t)(yy) * 98304 + (dx) * 768); \
        dst.x = h2f(u.x); dst.y = h2f(u.y); dst.z = h2f(u.z); dst.w = h2f(u.w); }
#define LDROW(yy, d) { \
        if ((yy) < 0 || (yy) > 127) { d[0] = z4; d[1] = z4; d[2] = z4; } \
        else { \
            if (xm_ok) LDV(yy, -1, d[0]) else d[0] = z4; \
            LDV(yy, 0, d[1]); \
            if (xp_ok) LDV(yy, 1, d[2]) else d[2] = z4; } }
#define TAP(rv, j) \
        acc.x = fmaf(rv.x, wreg[0 * 9 + (j)], acc.x); \
        acc.y = fmaf(rv.y, wreg[1 * 9 + (j)], acc.y); \
        acc.z = fmaf(rv.z, wreg[2 * 9 + (j)], acc.z); \
        acc.w = fmaf(rv.w, wreg[3 * 9 + (j)], acc.w);

    LDROW(y0 - 1, r0)
    LDROW(y0, r1)

#pragma unroll
    for (int t = 0; t < 16; ++t) {
        const int y = y0 + t;
        LDROW(y + 1, r2)

        const size_t opx = ((((size_t)b << 14) + y * 128 + x) << 8) + c4;
        ushort4 av = *(const ushort4*)(attb + opx);
        float4 acc;
        acc.x = h2f(av.x) + bv.x; acc.y = h2f(av.y) + bv.y;
        acc.z = h2f(av.z) + bv.z; acc.w = h2f(av.w) + bv.w;

        TAP(r0[0], 0) TAP(r0[1], 1) TAP(r0[2], 2)
        TAP(r1[0], 3) TAP(r1[1], 4) TAP(r1[2], 5)
        TAP(r2[0], 6) TAP(r2[1], 7) TAP(r2[2], 8)

        ushort4 o;
        o.x = f2h(acc.x); o.y = f2h(acc.y); o.z = f2h(acc.z); o.w = f2h(acc.w);
        *(ushort4*)(attb + opx) = o;

        r0[0] = r1[0]; r0[1] = r1[1]; r0[2] = r1[2];
        r1[0] = r2[0]; r1[1] = r2[1]; r1[2] = r2[2];
    }
#undef LDV
#undef LDROW
#undef TAP
}

// ---------------------------------------------------------------------------
extern "C" void kernel_launch(void* const* d_in, const int* in_sizes, int n_in,
                              void* d_out, int out_size, void* d_ws, size_t ws_size,
                              hipStream_t stream) {
    const float* x     = (const float*)d_in[0];
    const float* w_qkv = (const float*)d_in[1];
    const float* w_proj= (const float*)d_in[2];
    const float* b_proj= (const float*)d_in[3];
    const float* w_dw  = (const float*)d_in[4];
    const float* b_dw  = (const float*)d_in[5];
    const float* pp_w  = (const float*)d_in[6];
    const float* pp_b  = (const float*)d_in[7];
    const float* ln1_g = (const float*)d_in[8];
    const float* ln1_b = (const float*)d_in[9];
    const float* l1_w  = (const float*)d_in[10];
    const float* l1_b  = (const float*)d_in[11];
    const float* ln2_g = (const float*)d_in[12];
    const float* ln2_b = (const float*)d_in[13];
    const float* l2_w  = (const float*)d_in[14];
    const float* l2_b  = (const float*)d_in[15];
    const float* ln3_g = (const float*)d_in[16];
    const float* ln3_b = (const float*)d_in[17];
    const float* l3_w  = (const float*)d_in[18];
    const float* l3_b  = (const float*)d_in[19];

    // Workspace layout (~162.5 MiB):
    float* T2  = (float*)d_ws;                               // 524,288 f (swapped frag layout)
    unsigned short* qkvb = (unsigned short*)(T2 + 524288);   // 65536*768 sh (96 MiB, fp16)
    unsigned short* attb = qkvb + (size_t)NROWS * 768;       // 65536*256 sh (32 MiB, fp16)
    unsigned short* xh   = attb + (size_t)NROWS * 256;       // 32 MiB fp16
    unsigned short* wqh  = xh + (size_t)NROWS * 256;         // 196,608 sh
    unsigned short* wph  = wqh + 768 * 256;                  // 65,536 sh

    // T2 bias table (pos MLP fused per-thread, validated R10)
    rpb_kernel<<<dim3(256, 4, 2), 256, 0, stream>>>(pp_w, pp_b, ln1_g, ln1_b, l1_w, l1_b,
                                                    ln2_g, ln2_b, l2_w, l2_b, ln3_g, ln3_b,
                                                    l3_w, l3_b, T2);
    // both weight transposes in one launch (validated R10)
    convw_all<<<1024, 256, 0, stream>>>(w_qkv, w_proj, wqh, wph);
    // x -> fp16 (async-staging prerequisite; R10 lesson)
    convx_kernel<<<NROWS / 4, 256, 0, stream>>>(x, xh);
    // qkv_f16 = xh @ w_qkv   (single-term fp16; q-cols pre-scaled by SCALE2)
    gemm_f16<<<(NROWS / 128) * 6, 256, 0, stream>>>(xh, wqh, qkvb, 768, 6);
    // window attention -> attb (fp16, R6-validated qt-outer schedule)
    attn_mfma<<<dim3(256, 4, 2), 256, 0, stream>>>(qkvb, T2, attb);
    // LePE += depthwise conv on V (fp16 RMW, column-sliding-window)
    lepe_kernel<<<1024, 256, 0, stream>>>(qkvb, w_dw, b_dw, attb);
    // d_out = attb @ w_proj + b_proj  (single-term fp16, fp32 out, direct to d_out)
    gemm_proj<<<(NROWS / 128) * 2, 256, 0, stream>>>(attb, wph, (float*)d_out, b_proj);
}

// Round 12
// 299.294 us; speedup vs baseline: 1.0875x; 1.0374x over previous
//
#include <hip/hip_runtime.h>
#include <hip/hip_bf16.h>
#include <math.h>

// Problem constants (H=W=128 passed as inputs but fixed for this problem)
#define B_ 4
#define HH 128
#define WW 128
#define CC 256
#define LL (HH * WW)          // 16384
#define NROWS (B_ * LL)       // 65536
#define NREL 945              // (2*8-1)*(2*32-1)
#define SCALE 0.17677669529663687f  // 32^-0.5
#define LOG2E 1.4426950408889634f
#define SCALE2 (0.17677669529663687f * 1.4426950408889634f)  // SCALE * log2(e)

typedef __attribute__((ext_vector_type(8))) _Float16 half8;
typedef __attribute__((ext_vector_type(2))) __fp16 fp16x2;
typedef __attribute__((ext_vector_type(4))) float f32x4;

// fp16 <-> fp32 (RTNE via v_cvt)
__device__ __forceinline__ unsigned short f2h(float f) {
    union { _Float16 h; unsigned short u; } v;
    v.h = (_Float16)f;
    return v.u;
}
__device__ __forceinline__ float h2f(unsigned short u) {
    union { unsigned short u; _Float16 h; } v;
    v.u = u;
    return (float)v.h;
}
// raw v_exp_f32: computes 2^x. Validated in the R6 attn schedule (6 rounds);
// do NOT move into other schedules without re-validation (R7 lesson).
__device__ __forceinline__ float exp2_raw(float x) {
    float r;
    asm("v_exp_f32 %0, %1" : "=v"(r) : "v"(x));
    return r;
}
// async global->LDS, 16 B per lane (dest = wave-uniform base + lane*16)
__device__ __forceinline__ void gl_lds16(const unsigned short* g, unsigned short* l) {
    __builtin_amdgcn_global_load_lds((const __attribute__((address_space(1))) void*)g,
                                     (__attribute__((address_space(3))) void*)l, 16, 0, 0);
}

// ---------------------------------------------------------------------------
// DynamicPosBias MLP helpers (same expressions as the validated pos_kernel)
// ---------------------------------------------------------------------------
__device__ inline void ln_relu8(float* v, const float* g, const float* b) {
    float m = 0.f;
#pragma unroll
    for (int j = 0; j < 8; j++) m += v[j];
    m *= 0.125f;
    float var = 0.f;
#pragma unroll
    for (int j = 0; j < 8; j++) { float d = v[j] - m; var += d * d; }
    var *= 0.125f;
    float inv = 1.0f / sqrtf(var + 1e-5f);
#pragma unroll
    for (int j = 0; j < 8; j++) {
        float xn = (v[j] - m) * inv * g[j] + b[j];
        v[j] = xn > 0.f ? xn : 0.f;
    }
}

__device__ inline void mat8x8(const float* in, float* out, const float* w, const float* bias) {
#pragma unroll
    for (int j = 0; j < 8; j++) {
        float s = bias[j];
#pragma unroll
        for (int i = 0; i < 8; i++) s = fmaf(in[i], w[i * 8 + j], s);
        out[j] = s;
    }
}

// ---------------------------------------------------------------------------
// prep_kernel: three INDEPENDENT validated prep stages fused into ONE dispatch
// so they run concurrently (they were serialized on the stream before):
//   blocks [0, 16384)      : convx  — x fp32 -> xh fp16 (R11-validated body)
//   blocks [16384, 18432)  : rpb    — pos-MLP + T2 fragment table (R10/R11 body)
//   blocks [18432, 19456)  : convw  — both weight transposes (R10/R11 body)
// Per-branch code and per-thread arithmetic are byte-identical to R11.
// ---------------------------------------------------------------------------
__global__ __launch_bounds__(256) void prep_kernel(
        const float* __restrict__ x, unsigned short* __restrict__ xh,
        const float* __restrict__ pp_w, const float* __restrict__ pp_b,
        const float* __restrict__ ln1_g, const float* __restrict__ ln1_b,
        const float* __restrict__ l1_w, const float* __restrict__ l1_b,
        const float* __restrict__ ln2_g, const float* __restrict__ ln2_b,
        const float* __restrict__ l2_w, const float* __restrict__ l2_b,
        const float* __restrict__ ln3_g, const float* __restrict__ ln3_b,
        const float* __restrict__ l3_w, const float* __restrict__ l3_b,
        float* __restrict__ T2,
        const float* __restrict__ w_qkv, const float* __restrict__ w_proj,
        unsigned short* __restrict__ wqh, unsigned short* __restrict__ wph) {
    const int bb = blockIdx.x;
    if (bb < 16384) {
        // ---- convx ----
        size_t i = ((size_t)bb * 256 + threadIdx.x) * 4;
        float4 v = *(const float4*)(x + i);
        ushort4 h;
        h.x = f2h(v.x); h.y = f2h(v.y); h.z = f2h(v.z); h.w = f2h(v.w);
        *(ushort4*)(xh + i) = h;
    } else if (bb < 18432) {
        // ---- rpb (pos MLP fused per-thread) ----
        const int r = bb - 16384;
        const int m = threadIdx.x;       // key
        const int n = r & 255;           // query
        const int h = (r >> 8) & 3;
        const int br = r >> 10;
        const int logW = br ? 3 : 5;
        const int Wsp = 1 << logW;
        const int i_n = n >> logW, j_n = n & (Wsp - 1);
        const int i_m = m >> logW, j_m = m & (Wsp - 1);

        float dy = (float)(i_n - i_m);
        float dx = (float)(j_n - j_m);
        float p[8], t[8];
#pragma unroll
        for (int j = 0; j < 8; j++)
            p[j] = dy * pp_w[br * 16 + j] + dx * pp_w[br * 16 + 8 + j] + pp_b[br * 8 + j];
        ln_relu8(p, ln1_g + br * 8, ln1_b + br * 8);
        mat8x8(p, t, l1_w + br * 64, l1_b + br * 8);
        ln_relu8(t, ln2_g + br * 8, ln2_b + br * 8);
        mat8x8(t, p, l2_w + br * 64, l2_b + br * 8);
        ln_relu8(p, ln3_g + br * 8, ln3_b + br * 8);
        float s3 = l3_b[br * 4 + h];
#pragma unroll
        for (int i2 = 0; i2 < 8; i2++) s3 = fmaf(p[i2], l3_w[br * 32 + i2 * 4 + h], s3);

        float v = s3 * LOG2E;
        const int qchunk = n >> 4;
        const int l15q = n & 15;
        const int kc = m >> 5;
        const int lk = m & 31;
        const int s = (lk >> 4) & 1;
        const int quad = (lk & 15) >> 2;
        const int i = lk & 3;
        const int lane = quad * 16 + l15q;
        T2[(((size_t)(br * 4 + h) * 16 + qchunk) * 4096) + ((kc * 2 + s) * 256) + lane * 4 + i] = v;
    } else {
        // ---- convw (both weight transposes) ----
        const int cb = bb - 18432;
        if (cb < 768) {
            int idx = cb * 256 + threadIdx.x;       // n*K + k, Kd=256, Nd=768
            int n = idx >> 8, k = idx & 255;
            wqh[idx] = f2h(w_qkv[(size_t)k * 768 + n]);
        } else {
            int idx = (cb - 768) * 256 + threadIdx.x;  // Kd=256, Nd=256
            int n = idx >> 8, k = idx & 255;
            wph[idx] = f2h(w_proj[(size_t)k * 256 + n]);
        }
    }
}

// ---------------------------------------------------------------------------
// gemm_f16: C_f16[M][ldc] = A_f16 @ B_f16^T  (single-term, m97 structure,
// EXACT R6-validated kernel). BK=32, global_load_lds staging both operands.
// Epilogue: q-columns (col<256) pre-scaled by SCALE2 = scale*log2e.
// ---------------------------------------------------------------------------
__global__ __launch_bounds__(256) void gemm_f16(const unsigned short* __restrict__ A,
                                                const unsigned short* __restrict__ B,
                                                unsigned short* __restrict__ C,
                                                int ldc, int nblk) {
    const int K = 256;
    __shared__ unsigned short sA[4096];  // [128][32]
    __shared__ unsigned short sB[4096];

    const int tid = threadIdx.x;
    // XCD-aware bijective swizzle: grid (3072) % 8 == 0
    const int cpx = gridDim.x >> 3;
    const int bid = blockIdx.x;
    const int swz = (bid & 7) * cpx + (bid >> 3);
    const int nb = swz % nblk;                 // N fastest: A-tile L2 reuse
    const int mb = swz / nblk;
    const size_t blockM = (size_t)mb * 128;
    const int blockN = nb * 128;

    const int srow = tid >> 2;                 // staging row 0..63
    const int schunk = (tid & 3) * 8;          // k-chunk
    const unsigned short* pA = A + (blockM + srow) * K + schunk;
    const unsigned short* pB = B + (size_t)(blockN + srow) * K + schunk;
    const size_t rstep = (size_t)64 * K;

    const int w = tid >> 6;
    const int lane = tid & 63;
    const int quad = lane >> 4;
    const int l15 = lane & 15;
    const int wm = (w & 1) * 64;
    const int wn = (w >> 1) * 64;

    f32x4 acc[4][4];
#pragma unroll
    for (int i = 0; i < 4; i++)
#pragma unroll
        for (int j = 0; j < 4; j++) acc[i][j] = (f32x4){0.f, 0.f, 0.f, 0.f};

    for (int kb = 0; kb < K; kb += 32) {
        gl_lds16(pA + kb, sA + tid * 8);
        gl_lds16(pA + kb + rstep, sA + 2048 + tid * 8);
        gl_lds16(pB + kb, sB + tid * 8);
        gl_lds16(pB + kb + rstep, sB + 2048 + tid * 8);
        __syncthreads();

        half8 fa[4], fb[4];
#pragma unroll
        for (int i = 0; i < 4; i++) {
            fa[i] = *(const half8*)(sA + (wm + i * 16 + l15) * 32 + quad * 8);
            fb[i] = *(const half8*)(sB + (wn + i * 16 + l15) * 32 + quad * 8);
        }
#pragma unroll
        for (int i = 0; i < 4; i++)
#pragma unroll
            for (int j = 0; j < 4; j++)
                acc[i][j] = __builtin_amdgcn_mfma_f32_16x16x32_f16(fa[i], fb[j], acc[i][j], 0, 0, 0);
        __syncthreads();
    }

#pragma unroll
    for (int j = 0; j < 4; j++) {
        int col = blockN + wn + j * 16 + l15;
        // q-columns carry the softmax scale (wave-uniform branch)
        float sc = (ldc == 768 && col < 256) ? SCALE2 : 1.0f;
#pragma unroll
        for (int i = 0; i < 4; i++)
#pragma unroll
            for (int r = 0; r < 4; r++) {
                size_t row = blockM + wm + i * 16 + quad * 4 + r;
                C[row * ldc + col] = f2h(acc[i][j][r] * sc);
            }
    }
}

// ---------------------------------------------------------------------------
// gemm_proj: C_f32[M][256] = A_f16 @ B_f16^T + bias  (single-term, unchanged).
// ---------------------------------------------------------------------------
__global__ __launch_bounds__(256) void gemm_proj(const unsigned short* __restrict__ A,
                                                 const unsigned short* __restrict__ B,
                                                 float* __restrict__ C,
                                                 const float* __restrict__ bias) {
    const int K = 256;
    __shared__ unsigned short sA[4096];
    __shared__ unsigned short sB[4096];

    const int tid = threadIdx.x;
    const int cpx = gridDim.x >> 3;
    const int bid = blockIdx.x;
    const int swz = (bid & 7) * cpx + (bid >> 3);
    const int nb = swz & 1;
    const int mb = swz >> 1;
    const size_t blockM = (size_t)mb * 128;
    const int blockN = nb * 128;

    const int srow = tid >> 2;
    const int schunk = (tid & 3) * 8;
    const unsigned short* pA = A + (blockM + srow) * K + schunk;
    const unsigned short* pB = B + (size_t)(blockN + srow) * K + schunk;
    const size_t rstep = (size_t)64 * K;

    const int w = tid >> 6;
    const int lane = tid & 63;
    const int quad = lane >> 4;
    const int l15 = lane & 15;
    const int wm = (w & 1) * 64;
    const int wn = (w >> 1) * 64;

    f32x4 acc[4][4];
#pragma unroll
    for (int i = 0; i < 4; i++)
#pragma unroll
        for (int j = 0; j < 4; j++) acc[i][j] = (f32x4){0.f, 0.f, 0.f, 0.f};

    for (int kb = 0; kb < K; kb += 32) {
        gl_lds16(pA + kb, sA + tid * 8);
        gl_lds16(pA + kb + rstep, sA + 2048 + tid * 8);
        gl_lds16(pB + kb, sB + tid * 8);
        gl_lds16(pB + kb + rstep, sB + 2048 + tid * 8);
        __syncthreads();

        half8 fa[4], fb[4];
#pragma unroll
        for (int i = 0; i < 4; i++) {
            fa[i] = *(const half8*)(sA + (wm + i * 16 + l15) * 32 + quad * 8);
            fb[i] = *(const half8*)(sB + (wn + i * 16 + l15) * 32 + quad * 8);
        }
#pragma unroll
        for (int i = 0; i < 4; i++)
#pragma unroll
            for (int j = 0; j < 4; j++)
                acc[i][j] = __builtin_amdgcn_mfma_f32_16x16x32_f16(fa[i], fb[j], acc[i][j], 0, 0, 0);
        __syncthreads();
    }

#pragma unroll
    for (int j = 0; j < 4; j++) {
        int col = blockN + wn + j * 16 + l15;
        float bv = bias[col];
#pragma unroll
        for (int i = 0; i < 4; i++)
#pragma unroll
            for (int r = 0; r < 4; r++) {
                size_t row = blockM + wm + i * 16 + quad * 4 + r;
                C[row * 256 + col] = acc[i][j][r] + bv;
            }
    }
}

// ---------------------------------------------------------------------------
// MFMA window attention — EXACT R6/R9/R11-validated kernel (52.5 µs).
// Swapped-operand zero-shuffle softmax; qt-outer / kc-inner schedule.
// LDS: Ks 16384 + Vt 16896 = 33280 B -> 4 blocks/CU.
// ---------------------------------------------------------------------------
__global__ __launch_bounds__(256) void attn_mfma(const unsigned short* __restrict__ qkvb,
                                                 const float* __restrict__ T2,
                                                 unsigned short* __restrict__ attb) {
    __shared__ unsigned short Ks[256][32];    // [key][d], natural key order
    __shared__ unsigned short Vt[32][264];    // [d][key-slot(permuted)]

    const int tid = threadIdx.x;
    const int wi = blockIdx.x;   // b*64 + window
    const int h = blockIdx.y;    // 0..3
    const int br = blockIdx.z;   // 0..1
    const int logW = br ? 3 : 5;
    const int Wsp = 1 << logW;
    const int Hsp = 256 >> logW;
    const int logNWx = br ? 4 : 2;
    const int b = wi >> 6;
    const int win = wi & 63;
    const int wy = win >> logNWx;
    const int wx = win & ((1 << logNWx) - 1);
    const int ccol = br * 128 + h * 32;

#pragma unroll
    for (int it = 0; it < 8; ++it) {
        int n = it * 32 + (tid >> 3);
        int d4 = (tid & 7) * 4;
        int iy = n >> logW, ix = n & (Wsp - 1);
        size_t row = ((size_t)b * LL + (wy * Hsp + iy) * WW + wx * Wsp + ix) * 768;
        ushort4 kv = *(const ushort4*)(qkvb + row + 256 + ccol + d4);
        ushort4 vv = *(const ushort4*)(qkvb + row + 512 + ccol + d4);
        *(ushort4*)&Ks[n][d4] = kv;
        // slot-permuted key position within each 32-key chunk
        int pos = (n & ~31) + (((n & 12) << 1) | ((n & 16) >> 2) | (n & 3));
        Vt[d4 + 0][pos] = vv.x;
        Vt[d4 + 1][pos] = vv.y;
        Vt[d4 + 2][pos] = vv.z;
        Vt[d4 + 3][pos] = vv.w;
    }
    __syncthreads();

    const int w = tid >> 6;
    const int lane = tid & 63;
    const int quad = lane >> 4;
    const int l15 = lane & 15;
    const f32x4 zero = {0.f, 0.f, 0.f, 0.f};

#pragma unroll 1
    for (int qt = 0; qt < 4; ++qt) {
        const int qbase = qt * 64 + w * 16;
        const int qrow = qbase + l15;
        const int iyq = qrow >> logW, ixq = qrow & (Wsp - 1);
        const size_t qpix = (size_t)b * LL + (wy * Hsp + iyq) * WW + wx * Wsp + ixq;
        half8 qfrag = *(const half8*)(qkvb + qpix * 768 + ccol + quad * 8);

        // swapped-layout bias base for this wave's 16-query chunk
        const float* Tf = T2 + ((size_t)(br * 4 + h) * 16 + (qt * 4 + w)) * 4096 + lane * 4;

        f32x4 o0 = zero, o1 = zero;
        float rsum = 0.f;

#pragma unroll 2
        for (int kc = 0; kc < 8; ++kc) {
            const int kb0 = kc * 32;
            f32x4 b0 = *(const f32x4*)(Tf + kc * 512);
            f32x4 b1 = *(const f32x4*)(Tf + kc * 512 + 256);
            half8 kf0 = *(const half8*)&Ks[kb0 + l15][quad * 8];
            half8 kf1 = *(const half8*)&Ks[kb0 + 16 + l15][quad * 8];
            // S^T = K · Q^T + bias  (rows = keys, cols = queries)
            f32x4 s0 = __builtin_amdgcn_mfma_f32_16x16x32_f16(kf0, qfrag, b0, 0, 0, 0);
            f32x4 s1 = __builtin_amdgcn_mfma_f32_16x16x32_f16(kf1, qfrag, b1, 0, 0, 0);
            float e00 = exp2_raw(s0[0]), e01 = exp2_raw(s0[1]);
            float e02 = exp2_raw(s0[2]), e03 = exp2_raw(s0[3]);
            float e10 = exp2_raw(s1[0]), e11 = exp2_raw(s1[1]);
            float e12 = exp2_raw(s1[2]), e13 = exp2_raw(s1[3]);
            rsum += ((e00 + e01) + (e02 + e03)) + ((e10 + e11) + (e12 + e13));
            union { half8 h; unsigned u[4]; } pt;
            union { fp16x2 h; unsigned u; } cv;
            cv.h = __builtin_amdgcn_cvt_pkrtz(e00, e01); pt.u[0] = cv.u;
            cv.h = __builtin_amdgcn_cvt_pkrtz(e02, e03); pt.u[1] = cv.u;
            cv.h = __builtin_amdgcn_cvt_pkrtz(e10, e11); pt.u[2] = cv.u;
            cv.h = __builtin_amdgcn_cvt_pkrtz(e12, e13); pt.u[3] = cv.u;
            half8 vf0 = *(const half8*)&Vt[l15][kb0 + quad * 8];
            half8 vf1 = *(const half8*)&Vt[16 + l15][kb0 + quad * 8];
            // o^T = V^T · P^T  (rows = d, cols = queries)
            o0 = __builtin_amdgcn_mfma_f32_16x16x32_f16(vf0, pt.h, o0, 0, 0, 0);
            o1 = __builtin_amdgcn_mfma_f32_16x16x32_f16(vf1, pt.h, o1, 0, 0, 0);
        }

        // full row-sum for query l15: reduce across the 4 quads
        rsum += __shfl_xor(rsum, 16, 64);
        rsum += __shfl_xor(rsum, 32, 64);
        const float rinv = 1.0f / rsum;

        unsigned short* op = attb + qpix * 256 + ccol;
        ushort4 w0, w1;
        w0.x = f2h(o0[0] * rinv); w0.y = f2h(o0[1] * rinv);
        w0.z = f2h(o0[2] * rinv); w0.w = f2h(o0[3] * rinv);
        w1.x = f2h(o1[0] * rinv); w1.y = f2h(o1[1] * rinv);
        w1.z = f2h(o1[2] * rinv); w1.w = f2h(o1[3] * rinv);
        *(ushort4*)(op + quad * 4) = w0;
        *(ushort4*)(op + 16 + quad * 4) = w1;
    }
}

// ---------------------------------------------------------------------------
// LePE: depthwise 3x3 on fp16 V, += (with bias) into fp16 attb (RMW).
// Column-sliding-window (validated R5): 3 V loads + 1 RMW per pixel.
// ---------------------------------------------------------------------------
__global__ __launch_bounds__(256) void lepe_kernel(const unsigned short* __restrict__ qkvb,
                                                   const float* __restrict__ w_dw,
                                                   const float* __restrict__ b_dw,
                                                   unsigned short* __restrict__ attb) {
    const int lane = threadIdx.x & 63;
    const int wv = threadIdx.x >> 6;
    const int c4 = lane * 4;
    const int gid = blockIdx.x * 4 + wv;     // 4096 waves total
    const int ys = gid & 7;                  // y-strip of 16 rows
    const int x  = (gid >> 3) & 127;
    const int b  = gid >> 10;
    const int y0 = ys * 16;

    float wreg[36];
    const float* wp = w_dw + c4 * 9;
#pragma unroll
    for (int q = 0; q < 9; q++) {
        float4 t = *(const float4*)(wp + q * 4);
        wreg[q * 4 + 0] = t.x; wreg[q * 4 + 1] = t.y;
        wreg[q * 4 + 2] = t.z; wreg[q * 4 + 3] = t.w;
    }
    const float4 bv = *(const float4*)(b_dw + c4);
    const float4 z4 = {0.f, 0.f, 0.f, 0.f};
    const bool xm_ok = (x > 0), xp_ok = (x < 127);

    // V address of (b, yy, x+dx): vp + yy*98304 + dx*768
    const unsigned short* vp = qkvb + (((size_t)b << 14) + x) * 768 + 512 + c4;

    float4 r0[3], r1[3], r2[3];

#define LDV(yy, dx, dst) { \
        ushort4 u = *(const ushort4*)(vp + (ptrdiff_t)(yy) * 98304 + (dx) * 768); \
        dst.x = h2f(u.x); dst.y = h2f(u.y); dst.z = h2f(u.z); dst.w = h2f(u.w); }
#define LDROW(yy, d) { \
        if ((yy) < 0 || (yy) > 127) { d[0] = z4; d[1] = z4; d[2] = z4; } \
        else { \
            if (xm_ok) LDV(yy, -1, d[0]) else d[0] = z4; \
            LDV(yy, 0, d[1]); \
            if (xp_ok) LDV(yy, 1, d[2]) else d[2] = z4; } }
#define TAP(rv, j) \
        acc.x = fmaf(rv.x, wreg[0 * 9 + (j)], acc.x); \
        acc.y = fmaf(rv.y, wreg[1 * 9 + (j)], acc.y); \
        acc.z = fmaf(rv.z, wreg[2 * 9 + (j)], acc.z); \
        acc.w = fmaf(rv.w, wreg[3 * 9 + (j)], acc.w);

    LDROW(y0 - 1, r0)
    LDROW(y0, r1)

#pragma unroll
    for (int t = 0; t < 16; ++t) {
        const int y = y0 + t;
        LDROW(y + 1, r2)

        const size_t opx = ((((size_t)b << 14) + y * 128 + x) << 8) + c4;
        ushort4 av = *(const ushort4*)(attb + opx);
        float4 acc;
        acc.x = h2f(av.x) + bv.x; acc.y = h2f(av.y) + bv.y;
        acc.z = h2f(av.z) + bv.z; acc.w = h2f(av.w) + bv.w;

        TAP(r0[0], 0) TAP(r0[1], 1) TAP(r0[2], 2)
        TAP(r1[0], 3) TAP(r1[1], 4) TAP(r1[2], 5)
        TAP(r2[0], 6) TAP(r2[1], 7) TAP(r2[2], 8)

        ushort4 o;
        o.x = f2h(acc.x); o.y = f2h(acc.y); o.z = f2h(acc.z); o.w = f2h(acc.w);
        *(ushort4*)(attb + opx) = o;

        r0[0] = r1[0]; r0[1] = r1[1]; r0[2] = r1[2];
        r1[0] = r2[0]; r1[1] = r2[1]; r1[2] = r2[2];
    }
#undef LDV
#undef LDROW
#undef TAP
}

// ---------------------------------------------------------------------------
extern "C" void kernel_launch(void* const* d_in, const int* in_sizes, int n_in,
                              void* d_out, int out_size, void* d_ws, size_t ws_size,
                              hipStream_t stream) {
    const float* x     = (const float*)d_in[0];
    const float* w_qkv = (const float*)d_in[1];
    const float* w_proj= (const float*)d_in[2];
    const float* b_proj= (const float*)d_in[3];
    const float* w_dw  = (const float*)d_in[4];
    const float* b_dw  = (const float*)d_in[5];
    const float* pp_w  = (const float*)d_in[6];
    const float* pp_b  = (const float*)d_in[7];
    const float* ln1_g = (const float*)d_in[8];
    const float* ln1_b = (const float*)d_in[9];
    const float* l1_w  = (const float*)d_in[10];
    const float* l1_b  = (const float*)d_in[11];
    const float* ln2_g = (const float*)d_in[12];
    const float* ln2_b = (const float*)d_in[13];
    const float* l2_w  = (const float*)d_in[14];
    const float* l2_b  = (const float*)d_in[15];
    const float* ln3_g = (const float*)d_in[16];
    const float* ln3_b = (const float*)d_in[17];
    const float* l3_w  = (const float*)d_in[18];
    const float* l3_b  = (const float*)d_in[19];

    // Workspace layout (~162.5 MiB):
    float* T2  = (float*)d_ws;                               // 524,288 f (swapped frag layout)
    unsigned short* qkvb = (unsigned short*)(T2 + 524288);   // 65536*768 sh (96 MiB, fp16)
    unsigned short* attb = qkvb + (size_t)NROWS * 768;       // 65536*256 sh (32 MiB, fp16)
    unsigned short* xh   = attb + (size_t)NROWS * 256;       // 32 MiB fp16
    unsigned short* wqh  = xh + (size_t)NROWS * 256;         // 196,608 sh
    unsigned short* wph  = wqh + 768 * 256;                  // 65,536 sh

    // all prep (convx + rpb + convw) concurrent in ONE dispatch
    prep_kernel<<<19456, 256, 0, stream>>>(x, xh,
                                           pp_w, pp_b, ln1_g, ln1_b, l1_w, l1_b,
                                           ln2_g, ln2_b, l2_w, l2_b, ln3_g, ln3_b,
                                           l3_w, l3_b, T2,
                                           w_qkv, w_proj, wqh, wph);
    // qkv_f16 = xh @ w_qkv   (single-term fp16; q-cols pre-scaled by SCALE2)
    gemm_f16<<<(NROWS / 128) * 6, 256, 0, stream>>>(xh, wqh, qkvb, 768, 6);
    // window attention -> attb (fp16, R6-validated qt-outer schedule)
    attn_mfma<<<dim3(256, 4, 2), 256, 0, stream>>>(qkvb, T2, attb);
    // LePE += depthwise conv on V (fp16 RMW, column-sliding-window)
    lepe_kernel<<<1024, 256, 0, stream>>>(qkvb, w_dw, b_dw, attb);
    // d_out = attb @ w_proj + b_proj  (single-term fp16, fp32 out, direct to d_out)
    gemm_proj<<<(NROWS / 128) * 2, 256, 0, stream>>>(attb, wph, (float*)d_out, b_proj);
}